// Round 1
// baseline (21.770 us; speedup 1.0000x reference)
//
#include <hip/hip_runtime.h>
#include <math.h>

#define BB 4
#define SS 4096
#define DD 128
#define NEG_BIG 1e30f
#define JB 64   // rows per partial block

// ---------------------------------------------------------------------------
// Kernel 1: s[b*S+j] = dot(inputs[b,j,:], kernel[1,:,0]) + bias - (1-mask)*1e30
// One wave (64 lanes) per row; lane l handles float2 at d = 2l.
// ---------------------------------------------------------------------------
__global__ void score_kernel(const float* __restrict__ in,
                             const int* __restrict__ mask,
                             const float* __restrict__ kern,
                             const float* __restrict__ bias,
                             float* __restrict__ s) {
    int row  = (int)((blockIdx.x * blockDim.x + threadIdx.x) >> 6);  // 0..B*S-1
    int lane = threadIdx.x & 63;
    if (row >= BB * SS) return;
    const float* rp = in + (size_t)row * DD;
    float2 x = *(const float2*)(rp + lane * 2);
    float2 k = *(const float2*)(kern + DD + lane * 2);  // kernel[1,:,0]
    float acc = x.x * k.x + x.y * k.y;
    #pragma unroll
    for (int off = 32; off > 0; off >>= 1) acc += __shfl_xor(acc, off, 64);
    if (lane == 0) {
        float sc = acc + bias[0];
        if (mask[row] == 0) sc -= NEG_BIG;
        s[row] = sc;
    }
}

// ---------------------------------------------------------------------------
// Kernel 2: per-batch masked softmax over S elements, in place.
// One block (256 threads) per batch; each thread owns 16 strided elements.
// ---------------------------------------------------------------------------
__global__ void softmax_kernel(float* __restrict__ s) {
    int b = blockIdx.x;
    int t = threadIdx.x;  // 0..255
    float* sb = s + b * SS;

    float vals[16];
    float mloc = -INFINITY;
    #pragma unroll
    for (int k = 0; k < 16; ++k) {
        float x = sb[t + k * 256];
        vals[k] = x;
        mloc = fmaxf(mloc, x);
    }
    __shared__ float red[256];
    red[t] = mloc;
    __syncthreads();
    for (int o = 128; o > 0; o >>= 1) {
        if (t < o) red[t] = fmaxf(red[t], red[t + o]);
        __syncthreads();
    }
    float m = red[0];
    __syncthreads();

    float sloc = 0.0f;
    #pragma unroll
    for (int k = 0; k < 16; ++k) {
        float ex = expf(vals[k] - m);
        vals[k] = ex;
        sloc += ex;
    }
    red[t] = sloc;
    __syncthreads();
    for (int o = 128; o > 0; o >>= 1) {
        if (t < o) red[t] += red[t + o];
        __syncthreads();
    }
    float inv = 1.0f / red[0];
    #pragma unroll
    for (int k = 0; k < 16; ++k) sb[t + k * 256] = vals[k] * inv;
}

// ---------------------------------------------------------------------------
// Kernel 3: partial[b][blk][d] = sum over 64-row chunk of w[b,j]*in[b,j,d]
// 256 threads: lane (t&63) owns float2 at d=2*lane; row-group rg = t>>6.
// ---------------------------------------------------------------------------
__global__ void partial_kernel(const float* __restrict__ in,
                               const float* __restrict__ w,
                               float* __restrict__ partial) {
    int blk  = blockIdx.x;           // 0 .. B*(S/JB)-1
    int b    = blk >> 6;             // S/JB == 64
    int jblk = blk & 63;
    int j0   = jblk * JB;
    int t    = threadIdx.x;
    int lane = t & 63;
    int rg   = t >> 6;               // 0..3

    const float* base = in + ((size_t)(b * SS + j0)) * DD;
    const float* wb   = w + b * SS + j0;

    float2 acc = make_float2(0.0f, 0.0f);
    for (int j = rg; j < JB; j += 4) {
        float  wj = wb[j];
        float2 x  = *(const float2*)(base + (size_t)j * DD + lane * 2);
        acc.x += wj * x.x;
        acc.y += wj * x.y;
    }
    __shared__ float2 red[256];
    red[t] = acc;
    __syncthreads();
    if (rg == 0) {
        float2 a = red[lane];
        float2 c = red[64 + lane];
        float2 d = red[128 + lane];
        float2 e = red[192 + lane];
        float2 r;
        r.x = (a.x + c.x) + (d.x + e.x);
        r.y = (a.y + c.y) + (d.y + e.y);
        *(float2*)(partial + (size_t)blk * DD + lane * 2) = r;
    }
}

// ---------------------------------------------------------------------------
// Kernel 4: v[b][d] = sum over 64 partial blocks. 4 blocks x 128 threads.
// ---------------------------------------------------------------------------
__global__ void vreduce_kernel(const float* __restrict__ partial,
                               float* __restrict__ v) {
    int b = blockIdx.x;
    int d = threadIdx.x;  // 0..127
    const float* p = partial + (size_t)b * 64 * DD + d;
    float acc = 0.0f;
    #pragma unroll
    for (int k = 0; k < 64; ++k) acc += p[k * DD];
    v[b * DD + d] = acc;
}

// ---------------------------------------------------------------------------
// Kernel 5: out[b,i,:] = v[b,:] broadcast, float4 stores.
// total float4s = B*S*D/4 = 524288 -> 2048 blocks x 256 threads.
// ---------------------------------------------------------------------------
__global__ void bcast_kernel(const float* __restrict__ v,
                             float* __restrict__ out) {
    size_t idx = (size_t)blockIdx.x * blockDim.x + threadIdx.x;  // float4 index
    const int per_b = SS * (DD / 4);        // 131072
    int b   = (int)(idx / per_b);
    int rem = (int)(idx % per_b);
    int dg  = rem & (DD / 4 - 1);           // which float4 within the row
    float4 val = *(const float4*)(v + b * DD + dg * 4);
    ((float4*)out)[idx] = val;
}

extern "C" void kernel_launch(void* const* d_in, const int* in_sizes, int n_in,
                              void* d_out, int out_size, void* d_ws, size_t ws_size,
                              hipStream_t stream) {
    const float* in   = (const float*)d_in[0];  // [B,S,D] fp32
    const int*   mask = (const int*)d_in[1];    // [B,S]
    const float* kern = (const float*)d_in[2];  // [2,D,1]
    const float* bias = (const float*)d_in[3];  // [1]
    float* out = (float*)d_out;

    // Workspace layout (floats):
    //   s/w     : B*S          = 16384  (64 KB)   offset 0
    //   partial : B*64*D       = 32768  (128 KB)  offset 16384
    //   v       : B*D          = 512    (2 KB)    offset 49152
    float* s       = (float*)d_ws;
    float* partial = s + BB * SS;
    float* v       = partial + BB * 64 * DD;

    // 1. scores (wave per row): B*S waves, 4 waves/block
    score_kernel<<<dim3((BB * SS) / 4), dim3(256), 0, stream>>>(in, mask, kern, bias, s);
    // 2. per-batch softmax in place
    softmax_kernel<<<dim3(BB), dim3(256), 0, stream>>>(s);
    // 3. partial weighted sums: B * (S/JB) = 256 blocks
    partial_kernel<<<dim3(BB * (SS / JB)), dim3(256), 0, stream>>>(in, s, partial);
    // 4. final v reduction
    vreduce_kernel<<<dim3(BB), dim3(DD), 0, stream>>>(partial, v);
    // 5. broadcast to output
    bcast_kernel<<<dim3((BB * SS * DD / 4) / 256), dim3(256), 0, stream>>>(v, out);
}